// Round 3
// baseline (273.166 us; speedup 1.0000x reference)
//
#include <hip/hip_runtime.h>
#include <hip/hip_bf16.h>
#include <cstdint>
#include <cstddef>

typedef __attribute__((ext_vector_type(8))) short short8;
typedef __attribute__((ext_vector_type(4))) short short4v;
typedef __attribute__((ext_vector_type(4))) float floatx4;
typedef __attribute__((ext_vector_type(16))) float floatx16;
typedef unsigned short ushort_t;

#define LOG2E 1.44269504088896340736f

__device__ __forceinline__ unsigned short f2bf(float f) {
    unsigned u = __float_as_uint(f);
    u += 0x7FFFu + ((u >> 16) & 1u);   // RNE
    return (unsigned short)(u >> 16);
}
__device__ __forceinline__ float bf2f(unsigned short s) {
    return __uint_as_float(((unsigned)s) << 16);
}

// ---------------------------------------------------------------------------
// gemm_h v3: hT[b][o][j] = sum_k x[b][j][k]*W[o][k]  (bf16 out, o-major).
// Block = 64 j x 256 o, ALL K.  1024 threads = 16 waves = 4 waves/SIMD.
// Wave (jg = w>>2, og = w&3) owns 16j x 64o, acc[4].
// v3: W fp32 converted to bf16 during the LDS quarter-stage (wprep kernel
// fused away; W is 256KB, L2-resident across the 256 blocks).
// Epilogue: hT store + s_src/s_dst via 4-way cross-wave LDS reduction.
// ---------------------------------------------------------------------------
__global__ __launch_bounds__(1024) void gemm_h(const float* __restrict__ x,
                                               const float* __restrict__ W,
                                               ushort_t* __restrict__ hT,
                                               const float* __restrict__ a_src,
                                               const float* __restrict__ a_dst,
                                               float* __restrict__ s_src,
                                               float* __restrict__ s_dst) {
    const int tid = threadIdx.x;
    const int w = tid >> 6, lane = tid & 63;
    const int q = lane >> 4, t16 = lane & 15;
    const int jg = w >> 2, og = w & 3;

    __shared__ ushort_t wt[256][72];   // 256 o-rows x 64 k (quarter), +8 pad
    __shared__ float sred[2][4][64];   // cross-wave s_src/s_dst partials

    // load this wave's 16 x-rows (fp32 -> bf16 A-frags, all K upfront)
    const int jrow = blockIdx.x * 64 + jg * 16 + t16;
    const float* xr = x + (size_t)jrow * 256 + q * 8;
    short8 af[8];
#pragma unroll
    for (int kb = 0; kb < 8; ++kb) {
        float4 v0 = *(const float4*)(xr + kb * 32);
        float4 v1 = *(const float4*)(xr + kb * 32 + 4);
        short8 a;
        a[0] = (short)f2bf(v0.x); a[1] = (short)f2bf(v0.y);
        a[2] = (short)f2bf(v0.z); a[3] = (short)f2bf(v0.w);
        a[4] = (short)f2bf(v1.x); a[5] = (short)f2bf(v1.y);
        a[6] = (short)f2bf(v1.z); a[7] = (short)f2bf(v1.w);
        af[kb] = a;
    }

    floatx4 acc[4] = {};
#pragma unroll
    for (int kp = 0; kp < 4; ++kp) {
        if (kp) __syncthreads();       // protect wt overwrite
        // stage W K-quarter: fp32 -> bf16, 16 ushorts per thread
#pragma unroll
        for (int r = 0; r < 2; ++r) {
            int G = tid + 1024 * r;
            int row = G >> 3, g = G & 7;
            const float* wsrc = W + (size_t)row * 256 + kp * 64 + g * 8;
            float4 f0 = *(const float4*)(wsrc);
            float4 f1 = *(const float4*)(wsrc + 4);
            short8 wv;
            wv[0] = (short)f2bf(f0.x); wv[1] = (short)f2bf(f0.y);
            wv[2] = (short)f2bf(f0.z); wv[3] = (short)f2bf(f0.w);
            wv[4] = (short)f2bf(f1.x); wv[5] = (short)f2bf(f1.y);
            wv[6] = (short)f2bf(f1.z); wv[7] = (short)f2bf(f1.w);
            *(short8*)(&wt[row][g * 8]) = wv;
        }
        __syncthreads();
#pragma unroll
        for (int ks = 0; ks < 2; ++ks) {
#pragma unroll
            for (int ct = 0; ct < 4; ++ct) {
                short8 bf = *(const short8*)(&wt[og * 64 + ct * 16 + t16][ks * 32 + q * 8]);
                acc[ct] = __builtin_amdgcn_mfma_f32_16x16x32_bf16(af[kp * 2 + ks], bf, acc[ct], 0, 0, 0);
            }
        }
    }

    // hT store: D col=t16 -> o_local, row=q*4+r -> j_local
    const int jbase = blockIdx.x * 64 + jg * 16 + q * 4;   // flat b*2048+j
    const int b = jbase >> 11, jj = jbase & 2047;
#pragma unroll
    for (int ct = 0; ct < 4; ++ct) {
        const int o = og * 64 + ct * 16 + t16;
        short4v sv;
        sv[0] = (short)f2bf(acc[ct][0]);
        sv[1] = (short)f2bf(acc[ct][1]);
        sv[2] = (short)f2bf(acc[ct][2]);
        sv[3] = (short)f2bf(acc[ct][3]);
        *(short4v*)(hT + ((size_t)b * 256 + o) * 2048 + jj) = sv;
    }

    // s_src/s_dst partial dot over this wave's 64 o (then 16-lane shuffle)
    float psv[4] = {}, pdv[4] = {};
#pragma unroll
    for (int ct = 0; ct < 4; ++ct) {
        const int o = og * 64 + ct * 16 + t16;
        float as = a_src[o], ad = a_dst[o];
#pragma unroll
        for (int r = 0; r < 4; ++r) {
            psv[r] = __fmaf_rn(acc[ct][r], as, psv[r]);
            pdv[r] = __fmaf_rn(acc[ct][r], ad, pdv[r]);
        }
    }
#pragma unroll
    for (int m = 1; m < 16; m <<= 1) {
#pragma unroll
        for (int r = 0; r < 4; ++r) {
            psv[r] += __shfl_xor(psv[r], m);
            pdv[r] += __shfl_xor(pdv[r], m);
        }
    }
    if (t16 == 0) {
#pragma unroll
        for (int r = 0; r < 4; ++r) {
            sred[0][og][jg * 16 + q * 4 + r] = psv[r];
            sred[1][og][jg * 16 + q * 4 + r] = pdv[r];
        }
    }
    __syncthreads();
    if (tid < 64) {
        float ss = sred[0][0][tid] + sred[0][1][tid] + sred[0][2][tid] + sred[0][3][tid];
        float dd = sred[1][0][tid] + sred[1][1][tid] + sred[1][2][tid] + sred[1][3][tid];
        s_src[blockIdx.x * 64 + tid] = ss;
        s_dst[blockIdx.x * 64 + tid] = dd;
    }
}

// ---------------------------------------------------------------------------
// attn v4: O[i][o] = (1/l_i) sum_j p[i][j] * hT[o][j],
// p = exp2(lrelu(si+sd)*log2e) masked by adj.
// Block = 64 i x 256 o, grid (b=8, iblk=32); 1024 threads.
//
// v4 vs v3 (v3 measured: conflict fix + LDS-traffic cut -> ZERO time change;
// 3075 cyc/chunk vs ~500 of pipe work => exposed load latency, PF depth 1):
//  - hts LDS staging DELETED: A-frags (hT) read straight global->reg from the
//    XCD-L2-resident slice, prefetched one superchunk ahead (af0/af1 sets).
//    Removes ds_write + 48KB/chunk LDS traffic + the hreg vmcnt(0) stall.
//  - superchunk = 64 j (32 barriers instead of 64); ps[2][64][72] dbuf
//    (rows 144B = 16B-aligned for b128; same bank structure v3 measured ok).
//  - adj int4 prefetched TWO superchunks ahead (aE/aO, unroll-2 body):
//    latency window ~2 superchunks > 900cyc HBM miss. Tail clamped in-bounds.
//  - produce: 4 p/thread (ip=tid>>4, j=jq*4+e); lsum reduced over 16-lane
//    groups at the end.  Numerics identical (same RNE, same MFMA j-order).
// ---------------------------------------------------------------------------
__global__ __launch_bounds__(1024) void attn(const ushort_t* __restrict__ hT,
                                             const int* __restrict__ adj,
                                             const float* __restrict__ s_src,
                                             const float* __restrict__ s_dst,
                                             float* __restrict__ out) {
    const int tid = threadIdx.x;           // 0..1023
    const int w = tid >> 6;                // wave 0..15
    const int lane = tid & 63;
    const int l5 = lane & 31, hi = lane >> 5;
    const int b = blockIdx.x;
    const int i0 = blockIdx.y * 64;

    __shared__ ushort_t ps[2][64][72];     // 18.4 KB, 144B rows (b128-aligned)
    __shared__ float sdl[2048];            // s_dst * log2e : 8 KB
    __shared__ float rls[64];              // row sums of p

    // stage s_dst*log2e (2 floats/thread)
    const float* sdb = s_dst + (size_t)b * 2048;
    {
        int idx = tid * 2;
        float2 v = *(const float2*)(sdb + idx);
        v.x *= LOG2E; v.y *= LOG2E;
        *(float2*)(&sdl[idx]) = v;
    }

    // p-producer mapping: row ip = tid>>4 (0..63), j = sc*64 + jq*4 + e
    const int ip = tid >> 4, jq = tid & 15;
    const float si = s_src[(size_t)b * 2048 + i0 + ip] * LOG2E;
    const int* adjr = adj + ((size_t)b * 2048 + i0 + ip) * 2048 + jq * 4;

    // consumer mapping: wave tile 32 i x 32 o; A-frags direct from global hT
    const int osub = (w & 7) * 32, ih = (w >> 3) * 32;
    const ushort_t* hTg = hT + ((size_t)b * 256 + osub + l5) * 2048 + hi * 8;

    floatx16 acc = {};
    float lsum = 0.f;
    int4 aE, aO;          // adj prefetch, 2 superchunks deep
    short8 af0[4], af1[4];  // hT A-frags, 1 superchunk deep

    // prologue: adj sc0,sc1; A-frags sc0
    aE = *(const int4*)(adjr);
    aO = *(const int4*)(adjr + 64);
#pragma unroll
    for (int ks = 0; ks < 4; ++ks)
        af0[ks] = *(const short8*)(hTg + ks * 16);
    __syncthreads();   // sdl ready

#pragma unroll 1
    for (int it = 0; it < 16; ++it) {
        const int sc = it * 2;
        // ================= even superchunk (buf 0, adj aE, frags af0) =====
        {
            float4 sd = *(const float4*)(&sdl[sc * 64 + jq * 4]);
            float sv[4] = {sd.x, sd.y, sd.z, sd.w};
            int mv[4] = {aE.x, aE.y, aE.z, aE.w};
            short4v pv;
#pragma unroll
            for (int e = 0; e < 4; ++e) {
                float t = si + sv[e];
                float lr = fmaxf(t, 0.2f * t);
                float pe = __builtin_amdgcn_exp2f(lr);
                pe = (mv[e] != 0) ? pe : 0.0f;
                unsigned short u = f2bf(pe);
                lsum += bf2f(u);
                pv[e] = (short)u;
            }
            *(short4v*)(&ps[0][ip][jq * 4]) = pv;
        }
        {   // reload aE for sc+2 (clamped in-bounds; clamp value unused)
            const int nc = (sc + 2 < 32) ? sc + 2 : 31;
            aE = *(const int4*)(adjr + (size_t)nc * 64);
        }
#pragma unroll
        for (int ks = 0; ks < 4; ++ks)      // prefetch frags for sc+1
            af1[ks] = *(const short8*)(hTg + (size_t)(sc + 1) * 64 + ks * 16);
        __syncthreads();
#pragma unroll
        for (int ks = 0; ks < 4; ++ks) {
            short8 bfr = *(const short8*)(&ps[0][ih + l5][ks * 16 + hi * 8]);
            acc = __builtin_amdgcn_mfma_f32_32x32x16_bf16(af0[ks], bfr, acc, 0, 0, 0);
        }
        // ================= odd superchunk (buf 1, adj aO, frags af1) ======
        {
            float4 sd = *(const float4*)(&sdl[(sc + 1) * 64 + jq * 4]);
            float sv[4] = {sd.x, sd.y, sd.z, sd.w};
            int mv[4] = {aO.x, aO.y, aO.z, aO.w};
            short4v pv;
#pragma unroll
            for (int e = 0; e < 4; ++e) {
                float t = si + sv[e];
                float lr = fmaxf(t, 0.2f * t);
                float pe = __builtin_amdgcn_exp2f(lr);
                pe = (mv[e] != 0) ? pe : 0.0f;
                unsigned short u = f2bf(pe);
                lsum += bf2f(u);
                pv[e] = (short)u;
            }
            *(short4v*)(&ps[1][ip][jq * 4]) = pv;
        }
        {   // reload aO for sc+3 (clamped)
            const int nc = (sc + 3 < 32) ? sc + 3 : 31;
            aO = *(const int4*)(adjr + (size_t)nc * 64);
        }
        {   // prefetch frags for sc+2 (clamped)
            const int na = (sc + 2 < 32) ? sc + 2 : 31;
#pragma unroll
            for (int ks = 0; ks < 4; ++ks)
                af0[ks] = *(const short8*)(hTg + (size_t)na * 64 + ks * 16);
        }
        __syncthreads();
#pragma unroll
        for (int ks = 0; ks < 4; ++ks) {
            short8 bfr = *(const short8*)(&ps[1][ih + l5][ks * 16 + hi * 8]);
            acc = __builtin_amdgcn_mfma_f32_32x32x16_bf16(af1[ks], bfr, acc, 0, 0, 0);
        }
    }

    // row sums: row ip's j-columns live in the 16 lanes of its jq-group
#pragma unroll
    for (int m = 1; m < 16; m <<= 1) lsum += __shfl_xor(lsum, m);
    if (jq == 0) rls[ip] = lsum;
    __syncthreads();

    // epilogue: D col=l5 -> i_local, row=(reg&3)+8*(reg>>2)+4*hi -> o_local
    {
        const int i = ih + l5;
        const float s = rls[i];
        const float rl = (s > 0.f) ? 1.0f / s : 0.0f;
        float* orow = out + ((size_t)b * 2048 + i0 + i) * 256 + osub;
#pragma unroll
        for (int rq = 0; rq < 4; ++rq) {
            floatx4 v;
            v[0] = acc[rq * 4 + 0] * rl;
            v[1] = acc[rq * 4 + 1] * rl;
            v[2] = acc[rq * 4 + 2] * rl;
            v[3] = acc[rq * 4 + 3] * rl;
            *(floatx4*)(orow + rq * 8 + hi * 4) = v;
        }
    }
}

extern "C" void kernel_launch(void* const* d_in, const int* in_sizes, int n_in,
                              void* d_out, int out_size, void* d_ws, size_t ws_size,
                              hipStream_t stream) {
    const float* x     = (const float*)d_in[0];
    const int*   adj   = (const int*)d_in[1];
    const float* W     = (const float*)d_in[2];
    const float* a_src = (const float*)d_in[3];
    const float* a_dst = (const float*)d_in[4];
    float* out = (float*)d_out;

    // 8.125 MB scratch: hT (8 MB) + s_src/s_dst (64 KB each)
    char* ws = (char*)d_ws;
    ushort_t* hT = (ushort_t*)ws;                                   // [0, 8M)
    float* s_src = (float*)(ws + (size_t)8 * 1024 * 1024);          // 64 KB
    float* s_dst = s_src + 16384;                                   // 64 KB

    gemm_h<<<256, 1024, 0, stream>>>(x, W, hT, a_src, a_dst, s_src, s_dst);
    attn<<<dim3(8, 32), 1024, 0, stream>>>(hT, adj, s_src, s_dst, out);
}

// Round 4
// 271.254 us; speedup vs baseline: 1.0070x; 1.0070x over previous
//
#include <hip/hip_runtime.h>
#include <hip/hip_bf16.h>
#include <cstdint>
#include <cstddef>

typedef __attribute__((ext_vector_type(8))) short short8;
typedef __attribute__((ext_vector_type(4))) short short4v;
typedef __attribute__((ext_vector_type(4))) float floatx4;
typedef __attribute__((ext_vector_type(16))) float floatx16;
typedef unsigned short ushort_t;

#define LOG2E 1.44269504088896340736f

__device__ __forceinline__ unsigned short f2bf(float f) {
    unsigned u = __float_as_uint(f);
    u += 0x7FFFu + ((u >> 16) & 1u);   // RNE
    return (unsigned short)(u >> 16);
}
__device__ __forceinline__ float bf2f(unsigned short s) {
    return __uint_as_float(((unsigned)s) << 16);
}

// ---------------------------------------------------------------------------
// gemm_h v3 (unchanged, R3-passing): hT[b][o][j] = sum_k x[b][j][k]*W[o][k]
// (bf16 out, o-major).  Block = 64 j x 256 o, 1024 threads, 16 waves.
// W fp32->bf16 during LDS quarter-stage.  Epilogue: hT + s_src/s_dst.
// ---------------------------------------------------------------------------
__global__ __launch_bounds__(1024) void gemm_h(const float* __restrict__ x,
                                               const float* __restrict__ W,
                                               ushort_t* __restrict__ hT,
                                               const float* __restrict__ a_src,
                                               const float* __restrict__ a_dst,
                                               float* __restrict__ s_src,
                                               float* __restrict__ s_dst) {
    const int tid = threadIdx.x;
    const int w = tid >> 6, lane = tid & 63;
    const int q = lane >> 4, t16 = lane & 15;
    const int jg = w >> 2, og = w & 3;

    __shared__ ushort_t wt[256][72];   // 256 o-rows x 64 k (quarter), +8 pad
    __shared__ float sred[2][4][64];   // cross-wave s_src/s_dst partials

    const int jrow = blockIdx.x * 64 + jg * 16 + t16;
    const float* xr = x + (size_t)jrow * 256 + q * 8;
    short8 af[8];
#pragma unroll
    for (int kb = 0; kb < 8; ++kb) {
        float4 v0 = *(const float4*)(xr + kb * 32);
        float4 v1 = *(const float4*)(xr + kb * 32 + 4);
        short8 a;
        a[0] = (short)f2bf(v0.x); a[1] = (short)f2bf(v0.y);
        a[2] = (short)f2bf(v0.z); a[3] = (short)f2bf(v0.w);
        a[4] = (short)f2bf(v1.x); a[5] = (short)f2bf(v1.y);
        a[6] = (short)f2bf(v1.z); a[7] = (short)f2bf(v1.w);
        af[kb] = a;
    }

    floatx4 acc[4] = {};
#pragma unroll
    for (int kp = 0; kp < 4; ++kp) {
        if (kp) __syncthreads();
#pragma unroll
        for (int r = 0; r < 2; ++r) {
            int G = tid + 1024 * r;
            int row = G >> 3, g = G & 7;
            const float* wsrc = W + (size_t)row * 256 + kp * 64 + g * 8;
            float4 f0 = *(const float4*)(wsrc);
            float4 f1 = *(const float4*)(wsrc + 4);
            short8 wv;
            wv[0] = (short)f2bf(f0.x); wv[1] = (short)f2bf(f0.y);
            wv[2] = (short)f2bf(f0.z); wv[3] = (short)f2bf(f0.w);
            wv[4] = (short)f2bf(f1.x); wv[5] = (short)f2bf(f1.y);
            wv[6] = (short)f2bf(f1.z); wv[7] = (short)f2bf(f1.w);
            *(short8*)(&wt[row][g * 8]) = wv;
        }
        __syncthreads();
#pragma unroll
        for (int ks = 0; ks < 2; ++ks) {
#pragma unroll
            for (int ct = 0; ct < 4; ++ct) {
                short8 bf = *(const short8*)(&wt[og * 64 + ct * 16 + t16][ks * 32 + q * 8]);
                acc[ct] = __builtin_amdgcn_mfma_f32_16x16x32_bf16(af[kp * 2 + ks], bf, acc[ct], 0, 0, 0);
            }
        }
    }

    const int jbase = blockIdx.x * 64 + jg * 16 + q * 4;   // flat b*2048+j
    const int b = jbase >> 11, jj = jbase & 2047;
#pragma unroll
    for (int ct = 0; ct < 4; ++ct) {
        const int o = og * 64 + ct * 16 + t16;
        short4v sv;
        sv[0] = (short)f2bf(acc[ct][0]);
        sv[1] = (short)f2bf(acc[ct][1]);
        sv[2] = (short)f2bf(acc[ct][2]);
        sv[3] = (short)f2bf(acc[ct][3]);
        *(short4v*)(hT + ((size_t)b * 256 + o) * 2048 + jj) = sv;
    }

    float psv[4] = {}, pdv[4] = {};
#pragma unroll
    for (int ct = 0; ct < 4; ++ct) {
        const int o = og * 64 + ct * 16 + t16;
        float as = a_src[o], ad = a_dst[o];
#pragma unroll
        for (int r = 0; r < 4; ++r) {
            psv[r] = __fmaf_rn(acc[ct][r], as, psv[r]);
            pdv[r] = __fmaf_rn(acc[ct][r], ad, pdv[r]);
        }
    }
#pragma unroll
    for (int m = 1; m < 16; m <<= 1) {
#pragma unroll
        for (int r = 0; r < 4; ++r) {
            psv[r] += __shfl_xor(psv[r], m);
            pdv[r] += __shfl_xor(pdv[r], m);
        }
    }
    if (t16 == 0) {
#pragma unroll
        for (int r = 0; r < 4; ++r) {
            sred[0][og][jg * 16 + q * 4 + r] = psv[r];
            sred[1][og][jg * 16 + q * 4 + r] = pdv[r];
        }
    }
    __syncthreads();
    if (tid < 64) {
        float ss = sred[0][0][tid] + sred[0][1][tid] + sred[0][2][tid] + sred[0][3][tid];
        float dd = sred[1][0][tid] + sred[1][1][tid] + sred[1][2][tid] + sred[1][3][tid];
        s_src[blockIdx.x * 64 + tid] = ss;
        s_dst[blockIdx.x * 64 + tid] = dd;
    }
}

// ---------------------------------------------------------------------------
// attn v5: O[i][o] = (1/l_i) sum_j p[i][j] * hT[o][j],
// p = exp2(lrelu(si+sd)*log2e) masked by adj.
//
// v5 root-cause fix: v2-v4 used grid=256 blocks = EXACTLY 1 block/CU ->
// single barrier domain, every vmcnt/barrier drain idled the whole CU
// (all pipes <20%, 3000-4000 cyc/chunk vs ~500 of work).  v4 also showed
// direct-global A-frags are line-scattered (32 lines/load) -> keep v3's
// LDS staging (coalesced stage + conflict-free ds_read_b128).
//
// Block = 32 i x 128 o, 256 threads (4 waves), grid (8 b, 64 iblk, 2 oblk)
// = 1024 blocks = 4 independent barrier domains/CU (LDS 33KB x4 = 133KB of
// 160KB; VGPR ~60 < 128 for 4 waves/SIMD).  While one block drains, three
// others issue.  Structure per chunk (32 j, 64 chunks) is v3-proven:
// stage hT chunk from regs (depth-1 prefetch), produce p (adj depth-2
// prefetch aE/aO), 1 barrier, 2x mfma_32x32x16 per wave (osub = w*32).
// ---------------------------------------------------------------------------
__global__ __launch_bounds__(256) void attn(const ushort_t* __restrict__ hT,
                                            const int* __restrict__ adj,
                                            const float* __restrict__ s_src,
                                            const float* __restrict__ s_dst,
                                            float* __restrict__ out) {
    const int tid = threadIdx.x;           // 0..255
    const int w = tid >> 6;                // wave 0..3
    const int lane = tid & 63;
    const int l5 = lane & 31, hi = lane >> 5;
    const int b = blockIdx.x;
    const int i0 = blockIdx.y * 32;
    const int ob = blockIdx.z * 128;

    __shared__ ushort_t hts[2][128][40];   // 128 o x 32 j (+8 pad) : 20 KB
    __shared__ ushort_t ps[2][32][40];     // 32 i x 32 j (+8 pad)  : 5 KB
    __shared__ float sdl[2048];            // s_dst * log2e          : 8 KB
    __shared__ float rls[32];              // row sums of p

    // stage s_dst*log2e (8 floats/thread)
    const float* sdb = s_dst + (size_t)b * 2048;
    {
        float4 v0 = *(const float4*)(sdb + tid * 8);
        float4 v1 = *(const float4*)(sdb + tid * 8 + 4);
        v0.x *= LOG2E; v0.y *= LOG2E; v0.z *= LOG2E; v0.w *= LOG2E;
        v1.x *= LOG2E; v1.y *= LOG2E; v1.z *= LOG2E; v1.w *= LOG2E;
        *(float4*)(&sdl[tid * 8]) = v0;
        *(float4*)(&sdl[tid * 8 + 4]) = v1;
    }

    // p-producer mapping: row ip = tid>>3 (0..31), j = c*32 + jq*4 + e
    const int ip = tid >> 3, jq = tid & 7;
    const float si = s_src[(size_t)b * 2048 + i0 + ip] * LOG2E;
    const int* adjr = adj + ((size_t)b * 2048 + i0 + ip) * 2048 + jq * 4;

    // hT stager mapping: 128 rows x 4 segs(8j) = 512 int4s, 2/thread
    const int srow = tid >> 2, sseg = tid & 3;
    const ushort_t* hTg0 = hT + ((size_t)b * 256 + ob + srow) * 2048 + sseg * 8;
    const ushort_t* hTg1 = hTg0 + (size_t)64 * 2048;

    // consumer mapping: wave tile 32 i x 32 o, osub = w*32
    const int osub = w * 32;

    floatx16 acc = {};
    float lsum = 0.f;
    int4 aE, aO;       // adj prefetch, 2 chunks deep
    int4 hA0, hA1;     // hT stage regs, 1 chunk deep

    // prologue: adj chunks 0,1; hT chunk 0
    aE = *(const int4*)(adjr);
    aO = *(const int4*)(adjr + 32);
    hA0 = *(const int4*)(hTg0);
    hA1 = *(const int4*)(hTg1);
    __syncthreads();   // sdl ready

#pragma unroll 1
    for (int it = 0; it < 32; ++it) {
        const int c = it * 2;
        // ================= even chunk c (buf 0, adj aE) ====================
        *(int4*)(&hts[0][srow][sseg * 8]) = hA0;
        *(int4*)(&hts[0][srow + 64][sseg * 8]) = hA1;
        {
            float4 sd = *(const float4*)(&sdl[c * 32 + jq * 4]);
            float sv[4] = {sd.x, sd.y, sd.z, sd.w};
            int mv[4] = {aE.x, aE.y, aE.z, aE.w};
            short4v pv;
#pragma unroll
            for (int e = 0; e < 4; ++e) {
                float t = si + sv[e];
                float lr = fmaxf(t, 0.2f * t);
                float pe = __builtin_amdgcn_exp2f(lr);
                pe = (mv[e] != 0) ? pe : 0.0f;
                unsigned short u = f2bf(pe);
                lsum += bf2f(u);
                pv[e] = (short)u;
            }
            *(short4v*)(&ps[0][ip][jq * 4]) = pv;
        }
        // prefetch: hT chunk c+1; adj chunk c+2
        hA0 = *(const int4*)(hTg0 + (size_t)(c + 1) * 32);
        hA1 = *(const int4*)(hTg1 + (size_t)(c + 1) * 32);
        aE = *(const int4*)(adjr + (size_t)((c + 2 < 64) ? c + 2 : 63) * 32);
        __syncthreads();
#pragma unroll
        for (int ks = 0; ks < 2; ++ks) {
            short8 afr = *(const short8*)(&hts[0][osub + l5][ks * 16 + hi * 8]);
            short8 bfr = *(const short8*)(&ps[0][l5][ks * 16 + hi * 8]);
            acc = __builtin_amdgcn_mfma_f32_32x32x16_bf16(afr, bfr, acc, 0, 0, 0);
        }
        // ================= odd chunk c+1 (buf 1, adj aO) ===================
        *(int4*)(&hts[1][srow][sseg * 8]) = hA0;
        *(int4*)(&hts[1][srow + 64][sseg * 8]) = hA1;
        {
            float4 sd = *(const float4*)(&sdl[(c + 1) * 32 + jq * 4]);
            float sv[4] = {sd.x, sd.y, sd.z, sd.w};
            int mv[4] = {aO.x, aO.y, aO.z, aO.w};
            short4v pv;
#pragma unroll
            for (int e = 0; e < 4; ++e) {
                float t = si + sv[e];
                float lr = fmaxf(t, 0.2f * t);
                float pe = __builtin_amdgcn_exp2f(lr);
                pe = (mv[e] != 0) ? pe : 0.0f;
                unsigned short u = f2bf(pe);
                lsum += bf2f(u);
                pv[e] = (short)u;
            }
            *(short4v*)(&ps[1][ip][jq * 4]) = pv;
        }
        // prefetch: hT chunk c+2; adj chunk c+3 (clamped in-bounds at tail)
        {
            const int nh = (c + 2 < 64) ? c + 2 : 63;
            hA0 = *(const int4*)(hTg0 + (size_t)nh * 32);
            hA1 = *(const int4*)(hTg1 + (size_t)nh * 32);
        }
        aO = *(const int4*)(adjr + (size_t)((c + 3 < 64) ? c + 3 : 63) * 32);
        __syncthreads();
#pragma unroll
        for (int ks = 0; ks < 2; ++ks) {
            short8 afr = *(const short8*)(&hts[1][osub + l5][ks * 16 + hi * 8]);
            short8 bfr = *(const short8*)(&ps[1][l5][ks * 16 + hi * 8]);
            acc = __builtin_amdgcn_mfma_f32_32x32x16_bf16(afr, bfr, acc, 0, 0, 0);
        }
    }

    // row sums: row ip's 32 j live in its 8 jq-lanes (chunk-accumulated)
#pragma unroll
    for (int m = 1; m < 8; m <<= 1) lsum += __shfl_xor(lsum, m);
    if (jq == 0) rls[ip] = lsum;
    __syncthreads();

    // epilogue: D col=l5 -> i_local, row=(reg&3)+8*(reg>>2)+4*hi -> o_local
    {
        const int i = l5;
        const float s = rls[i];
        const float rl = (s > 0.f) ? 1.0f / s : 0.0f;
        float* orow = out + ((size_t)b * 2048 + i0 + i) * 256 + ob + osub;
#pragma unroll
        for (int rq = 0; rq < 4; ++rq) {
            floatx4 v;
            v[0] = acc[rq * 4 + 0] * rl;
            v[1] = acc[rq * 4 + 1] * rl;
            v[2] = acc[rq * 4 + 2] * rl;
            v[3] = acc[rq * 4 + 3] * rl;
            *(floatx4*)(orow + rq * 8 + hi * 4) = v;
        }
    }
}

extern "C" void kernel_launch(void* const* d_in, const int* in_sizes, int n_in,
                              void* d_out, int out_size, void* d_ws, size_t ws_size,
                              hipStream_t stream) {
    const float* x     = (const float*)d_in[0];
    const int*   adj   = (const int*)d_in[1];
    const float* W     = (const float*)d_in[2];
    const float* a_src = (const float*)d_in[3];
    const float* a_dst = (const float*)d_in[4];
    float* out = (float*)d_out;

    // 8.125 MB scratch: hT (8 MB) + s_src/s_dst (64 KB each)
    char* ws = (char*)d_ws;
    ushort_t* hT = (ushort_t*)ws;                                   // [0, 8M)
    float* s_src = (float*)(ws + (size_t)8 * 1024 * 1024);          // 64 KB
    float* s_dst = s_src + 16384;                                   // 64 KB

    gemm_h<<<256, 1024, 0, stream>>>(x, W, hT, a_src, a_dst, s_src, s_dst);
    attn<<<dim3(8, 64, 2), 256, 0, stream>>>(hT, adj, s_src, s_dst, out);
}